// Round 9
// baseline (1453.403 us; speedup 1.0000x reference)
//
#include <hip/hip_runtime.h>
#include <hip/hip_bf16.h>

typedef __hip_bfloat16 bf16;
typedef __attribute__((ext_vector_type(8))) short short8;
typedef __attribute__((ext_vector_type(4))) float f32x4;

__device__ __forceinline__ short f2b(float v)
{
    union { bf16 b; short s; } u;
    u.b = __float2bfloat16(v);
    return u.s;
}
__device__ __forceinline__ float b2f(short s)
{
    union { short s; bf16 b; } u;
    u.s = s;
    return __bfloat162float(u.b);
}
__device__ __forceinline__ void splt(float v, short& hi, short& lo)
{
    hi = f2b(v);
    lo = f2b(v - b2f(hi));
}
__device__ __forceinline__ int bsw(int row, int g)
{
    return row * 40 + (((g + (row >> 3)) & 3) << 3);
}

// ---------------------------------------------------------------------------
// Dtype detector (validated r2): flag=1 -> fp32 storage, 0 -> bf16.
// ---------------------------------------------------------------------------
__global__ void detect_k(const unsigned short* __restrict__ p, int* __restrict__ flag)
{
    __shared__ int cnt;
    if (threadIdx.x == 0) cnt = 0;
    __syncthreads();
    int bad = 0;
    for (int i = threadIdx.x; i < 4096; i += 256) {
        unsigned short u = p[2 * i];
        int e = (u >> 7) & 0xFF;
        if (e != 0 && (e < 100 || e > 140)) bad++;
    }
    atomicAdd(&cnt, bad);
    __syncthreads();
    if (threadIdx.x == 0) *flag = (cnt > 1024) ? 1 : 0;
}

// ---------------------------------------------------------------------------
// Fused ingest (validated r5)
// ---------------------------------------------------------------------------
#define NSEG 24
struct IArgs {
    const void* src[NSEG];
    float* dst[NSEG];
    long start[NSEG + 1];
};

__global__ void ingest_all_k(IArgs a, const int* __restrict__ flag)
{
    long i = (long)blockIdx.x * 256 + threadIdx.x;
    if (i >= a.start[NSEG]) return;
    int s = 0;
#pragma unroll
    for (int j = 1; j < NSEG; j++) s += (i >= a.start[j]) ? 1 : 0;
    long idx = i - a.start[s];
    float v;
    if (*flag) v = ((const float*)a.src[s])[idx];
    else       v = __bfloat162float(((const bf16*)a.src[s])[idx]);
    a.dst[s][idx] = v;
}

// C[b][m][n] = bias[m] (or 0).  total = B*MN.
__global__ void fill_k(float* __restrict__ C, const float* __restrict__ bias,
                       long MN, int Nn, long total)
{
    long i = (long)blockIdx.x * 256 + threadIdx.x;
    if (i >= total) return;
    float v = 0.f;
    if (bias) {
        long r = i % MN;
        v = bias[(int)(r / Nn)];
    }
    C[i] = v;
}

// Tiled transpose: X[b][c][n] -> XT[b][n][c].  C=256. grid (N/32, 8, B), blk (32,8)
__global__ void tr_k(const float* __restrict__ X, float* __restrict__ XT, int N)
{
    __shared__ float t[32][33];
    int b = blockIdx.z, n0 = blockIdx.x * 32, c0 = blockIdx.y * 32;
    const float* Xb = X + (long)b * 256 * N;
    float* Tb = XT + (long)b * 256 * N;
    int tx = threadIdx.x, ty = threadIdx.y;
#pragma unroll
    for (int i = 0; i < 4; i++)
        t[ty + 8 * i][tx] = Xb[(long)(c0 + ty + 8 * i) * N + n0 + tx];
    __syncthreads();
#pragma unroll
    for (int i = 0; i < 4; i++)
        Tb[(long)(n0 + ty + 8 * i) * 256 + c0 + tx] = t[tx][ty + 8 * i];
}

// ---------------------------------------------------------------------------
// MFMA bf16 GEMM (validated r8) — non-DCN ops.
// ---------------------------------------------------------------------------
template <bool TRA, int BMODE, bool ACCUM, bool BIAS, int PREC, int KSPLIT>
__launch_bounds__(256)
__global__ void mgemm(const float* __restrict__ A, int lda, int ksA, long sA,
                      const void* __restrict__ Bsrc, int ldb, long sB,
                      float* __restrict__ C, int ldc, long sC,
                      const float* __restrict__ bias,
                      int M, int N, int K, int H, int wsh)
{
    __shared__ short As[PREC * 2560];
    __shared__ short Bs[PREC * 2560];

    const int bz = blockIdx.z;
    const float* Ab = A + (long)bz * sA;
    float* Cb = C + (long)bz * sC;
    const int mt = blockIdx.y / KSPLIT, ch = blockIdx.y % KSPLIT;
    const int m0 = mt * 64, n0 = blockIdx.x * 64;
    const int kchunk = K / KSPLIT;
    const int kbeg = ch * kchunk, kend = kbeg + kchunk;
    const int tid = threadIdx.x;

    f32x4 acc[2][2];
#pragma unroll
    for (int i = 0; i < 2; i++)
#pragma unroll
        for (int j = 0; j < 2; j++) acc[i][j] = (f32x4){0.f, 0.f, 0.f, 0.f};

    const int lane = tid & 63, wv = tid >> 6;
    const int moff = (wv & 1) * 32, noff = (wv >> 1) * 32;
    const int lr = lane & 15, lq = lane >> 4;
    const int mm = tid >> 2, kk0 = (tid & 3) * 8;
    const int nn = tid & 63, kg = tid >> 6;

    for (int k0 = kbeg; k0 < kend; k0 += 32) {
        // ---- stage A ----
        {
            float vv[8];
            if (m0 + mm < M) {
                if (!TRA) {
                    if (ksA == 1) {
                        const float4* s4 = (const float4*)(Ab + (long)(m0 + mm) * lda + k0 + kk0);
                        float4 v0 = s4[0], v1 = s4[1];
                        vv[0] = v0.x; vv[1] = v0.y; vv[2] = v0.z; vv[3] = v0.w;
                        vv[4] = v1.x; vv[5] = v1.y; vv[6] = v1.z; vv[7] = v1.w;
                    } else {
                        const float* s = Ab + (long)(m0 + mm) * lda + (long)(k0 + kk0) * ksA;
#pragma unroll
                        for (int j = 0; j < 8; j++) vv[j] = s[(long)j * ksA];
                    }
                } else {
#pragma unroll
                    for (int j = 0; j < 8; j++)
                        vv[j] = Ab[(long)(k0 + kk0 + j) * lda + m0 + mm];
                }
            } else {
#pragma unroll
                for (int j = 0; j < 8; j++) vv[j] = 0.f;
            }
            short8 hi, lo;
#pragma unroll
            for (int j = 0; j < 8; j++) { short h, l; splt(vv[j], h, l); hi[j] = h; lo[j] = l; }
            *(short8*)&As[mm * 40 + kk0] = hi;
            if (PREC == 2) *(short8*)&As[2560 + mm * 40 + kk0] = lo;
        }

        // ---- stage B ----
        if (BMODE == 1) {
            const float4* s4 = (const float4*)((const float*)Bsrc + (long)bz * sB +
                                               (long)(n0 + mm) * ldb + k0 + kk0);
            float4 v0 = s4[0], v1 = s4[1];
            float vv[8] = {v0.x, v0.y, v0.z, v0.w, v1.x, v1.y, v1.z, v1.w};
            short8 hi, lo;
#pragma unroll
            for (int j = 0; j < 8; j++) { short h, l; splt(vv[j], h, l); hi[j] = h; lo[j] = l; }
            int o = bsw(mm, tid & 3);
            *(short8*)&Bs[o] = hi;
            if (PREC == 2) *(short8*)&Bs[2560 + o] = lo;
        } else {
            float vv[8];
            if (BMODE == 0) {
#pragma unroll
                for (int j = 0; j < 8; j++)
                    vv[j] = ((const float*)Bsrc)[(long)bz * sB + (long)(k0 + kg * 8 + j) * ldb + n0 + nn];
            } else {  // BMODE 3: im2col
                int W = 1 << wsh;
                int n = n0 + nn;
                int hbase = n >> wsh, wbase = n & (W - 1);
#pragma unroll
                for (int j = 0; j < 8; j++) {
                    int kc = k0 + kg * 8 + j;
                    int c = kc / 9, tap = kc - 9 * c;
                    int h = hbase + tap / 3 - 1, w = wbase + tap % 3 - 1;
                    vv[j] = (h >= 0 && h < H && w >= 0 && w < W)
                          ? ((const float*)Bsrc)[(long)bz * sB + (long)c * ldb + (h << wsh) + w]
                          : 0.f;
                }
            }
            short8 hi, lo;
#pragma unroll
            for (int j = 0; j < 8; j++) { short h, l; splt(vv[j], h, l); hi[j] = h; lo[j] = l; }
            int o = bsw(nn, kg);
            *(short8*)&Bs[o] = hi;
            if (PREC == 2) *(short8*)&Bs[2560 + o] = lo;
        }
        __syncthreads();

        // ---- compute ----
        int rb0 = noff + lr, rb1 = noff + 16 + lr;
        short8 a0h = *(short8*)&As[(moff + lr) * 40 + lq * 8];
        short8 a1h = *(short8*)&As[(moff + 16 + lr) * 40 + lq * 8];
        short8 b0h = *(short8*)&Bs[bsw(rb0, lq)];
        short8 b1h = *(short8*)&Bs[bsw(rb1, lq)];
        acc[0][0] = __builtin_amdgcn_mfma_f32_16x16x32_bf16(a0h, b0h, acc[0][0], 0, 0, 0);
        acc[0][1] = __builtin_amdgcn_mfma_f32_16x16x32_bf16(a0h, b1h, acc[0][1], 0, 0, 0);
        acc[1][0] = __builtin_amdgcn_mfma_f32_16x16x32_bf16(a1h, b0h, acc[1][0], 0, 0, 0);
        acc[1][1] = __builtin_amdgcn_mfma_f32_16x16x32_bf16(a1h, b1h, acc[1][1], 0, 0, 0);
        if (PREC == 2) {
            short8 a0l = *(short8*)&As[2560 + (moff + lr) * 40 + lq * 8];
            short8 a1l = *(short8*)&As[2560 + (moff + 16 + lr) * 40 + lq * 8];
            short8 b0l = *(short8*)&Bs[2560 + bsw(rb0, lq)];
            short8 b1l = *(short8*)&Bs[2560 + bsw(rb1, lq)];
            acc[0][0] = __builtin_amdgcn_mfma_f32_16x16x32_bf16(a0h, b0l, acc[0][0], 0, 0, 0);
            acc[0][1] = __builtin_amdgcn_mfma_f32_16x16x32_bf16(a0h, b1l, acc[0][1], 0, 0, 0);
            acc[1][0] = __builtin_amdgcn_mfma_f32_16x16x32_bf16(a1h, b0l, acc[1][0], 0, 0, 0);
            acc[1][1] = __builtin_amdgcn_mfma_f32_16x16x32_bf16(a1h, b1l, acc[1][1], 0, 0, 0);
            acc[0][0] = __builtin_amdgcn_mfma_f32_16x16x32_bf16(a0l, b0h, acc[0][0], 0, 0, 0);
            acc[0][1] = __builtin_amdgcn_mfma_f32_16x16x32_bf16(a0l, b1h, acc[0][1], 0, 0, 0);
            acc[1][0] = __builtin_amdgcn_mfma_f32_16x16x32_bf16(a1l, b0h, acc[1][0], 0, 0, 0);
            acc[1][1] = __builtin_amdgcn_mfma_f32_16x16x32_bf16(a1l, b1h, acc[1][1], 0, 0, 0);
        }
        __syncthreads();
    }

    // ---- epilogue ----
#pragma unroll
    for (int mi = 0; mi < 2; mi++)
#pragma unroll
        for (int ni = 0; ni < 2; ni++) {
            int col = n0 + noff + ni * 16 + lr;
#pragma unroll
            for (int r = 0; r < 4; r++) {
                int row = m0 + moff + mi * 16 + lq * 4 + r;
                if (row < M) {
                    long o = (long)row * ldc + col;
                    float v = acc[mi][ni][r];
                    if (KSPLIT > 1) {
                        atomicAdd(&Cb[o], v);
                    } else {
                        if (BIAS) v += bias[row];
                        if (ACCUM) v += Cb[o];
                        Cb[o] = v;
                    }
                }
            }
        }
}

// ---------------------------------------------------------------------------
// DCN bilinear corner tables
// ---------------------------------------------------------------------------
__global__ void dcnw_k(const float* __restrict__ OO, float4* __restrict__ Tw,
                       int4* __restrict__ Ta, int N, int H, int W)
{
    long idx = (long)blockIdx.x * 256 + threadIdx.x;
    if (idx >= (long)16 * 9 * N) return;
    int b = (int)(idx / (9 * N));
    int r = (int)(idx % (9 * N));
    int tap = r / N, p = r % N;
    int h = p / W, w = p % W;
    const float* oob = OO + (long)b * 27 * N;
    float oy = oob[(2 * tap) * N + p];
    float ox = oob[(2 * tap + 1) * N + p];
    float mz = oob[(18 + tap) * N + p];
    float mask = 1.f / (1.f + expf(-mz));
    float y = (float)(h - 1 + tap / 3) + oy;
    float x = (float)(w - 1 + tap % 3) + ox;
    float y0 = floorf(y), x0 = floorf(x);
    float wy = y - y0, wx = x - x0;
    float ys[2] = {y0, y0 + 1.f};
    float xs[2] = {x0, x0 + 1.f};
    float wys[2] = {1.f - wy, wy};
    float wxs[2] = {1.f - wx, wx};
    float wv[4]; int av[4];
#pragma unroll
    for (int iy = 0; iy < 2; iy++)
#pragma unroll
        for (int ix = 0; ix < 2; ix++) {
            float yy = ys[iy], xx = xs[ix];
            bool valid = (yy >= 0.f) && (yy <= (float)(H - 1)) &&
                         (xx >= 0.f) && (xx <= (float)(W - 1));
            wv[iy * 2 + ix] = valid ? wys[iy] * wxs[ix] * mask : 0.f;
            int yc = (int)fminf(fmaxf(yy, 0.f), (float)(H - 1));
            int xc = (int)fminf(fmaxf(xx, 0.f), (float)(W - 1));
            av[iy * 2 + ix] = yc * W + xc;
        }
    Tw[idx] = (float4){wv[0], wv[1], wv[2], wv[3]};
    Ta[idx] = (int4){av[0], av[1], av[2], av[3]};
}

// DCN weight prepack to split-bf16 planes: Wh/Wl[o][tap*256+c]
__global__ void wre2_k(const float* __restrict__ W, short* __restrict__ Wh,
                       short* __restrict__ Wl)
{
    long idx = (long)blockIdx.x * 256 + threadIdx.x;
    if (idx >= 2304L * 256) return;
    int o = (int)(idx / 2304);
    int k = (int)(idx % 2304);
    int tap = k >> 8, c = k & 255;
    short h, l;
    splt(W[((long)o * 256 + c) * 9 + tap], h, l);
    Wh[idx] = h;
    Wl[idx] = l;
}

// ---------------------------------------------------------------------------
// Fused deformable conv v2: tile M=64 x N=256, K=2304 (72 steps of 32).
// A from prepacked bf16 hi/lo planes (no re-split, half the bytes).
// B sampled on the fly, lane = column (coalesced gathers).
// SWZ: 1-D grid of 256, XCD-aware decode (bid%8 -> 2 batches per XCD).
// KSPLIT>1: atomicAdd into bias-prefilled C.
// ---------------------------------------------------------------------------
template <int KSPLIT, bool SWZ>
__launch_bounds__(256)
__global__ void dcn2_k(const short* __restrict__ Wh, const short* __restrict__ Wl,
                       const float4* __restrict__ Tw, const int4* __restrict__ Ta,
                       const float* __restrict__ X, const float* __restrict__ bias,
                       float* __restrict__ C, int N)
{
    __shared__ short As[2 * 2560];   // [part][64][40]
    __shared__ short Bs[2 * 10240];  // [part][256][40]

    int bz, mt, ch, n0;
    if (SWZ) {
        int bid = blockIdx.x;
        int g = bid & 7, idx = bid >> 3;
        bz = g * 2 + (idx >> 4);
        int tile = idx & 15;
        mt = tile >> 2;
        n0 = (tile & 3) * 256;
        ch = 0;
    } else {
        bz = blockIdx.z;
        mt = blockIdx.y / KSPLIT;
        ch = blockIdx.y % KSPLIT;
        n0 = blockIdx.x * 256;
    }
    const int m0 = mt * 64;
    const int tid = threadIdx.x;
    const int lane = tid & 63, wv = tid >> 6;
    const int lr = lane & 15, lq = lane >> 4;
    const int arow = tid >> 2, akg = tid & 3;
    const float* Xb = X + (long)bz * 256 * N;
    float* Cb = C + (long)bz * 256 * N;

    f32x4 acc[4][4];
#pragma unroll
    for (int i = 0; i < 4; i++)
#pragma unroll
        for (int j = 0; j < 4; j++) acc[i][j] = (f32x4){0.f, 0.f, 0.f, 0.f};

    const int itc = 72 / KSPLIT;
    for (int kt = ch * itc; kt < ch * itc + itc; kt++) {
        int tap = kt >> 3, c0 = (kt & 7) * 32;
        // ---- stage A: bf16 planes, direct short8 copy ----
        {
            long o = (long)(m0 + arow) * 2304 + tap * 256 + c0 + akg * 8;
            *(short8*)&As[arow * 40 + akg * 8] = *(const short8*)&Wh[o];
            *(short8*)&As[2560 + arow * 40 + akg * 8] = *(const short8*)&Wl[o];
        }
        // ---- stage B: sample 32 channels for this thread's column ----
        {
            long ti = (long)(bz * 9 + tap) * N + n0 + tid;
            float4 w4 = Tw[ti];
            int4 a4 = Ta[ti];
            short8 h8[4], l8[4];
#pragma unroll
            for (int q = 0; q < 4; q++)
#pragma unroll
                for (int j = 0; j < 8; j++) {
                    const float* r = Xb + (long)(c0 + q * 8 + j) * N;
                    float v = w4.x * r[a4.x] + w4.y * r[a4.y] +
                              w4.z * r[a4.z] + w4.w * r[a4.w];
                    short hh, ll; splt(v, hh, ll);
                    h8[q][j] = hh; l8[q][j] = ll;
                }
#pragma unroll
            for (int q = 0; q < 4; q++) {
                *(short8*)&Bs[tid * 40 + q * 8] = h8[q];
                *(short8*)&Bs[10240 + tid * 40 + q * 8] = l8[q];
            }
        }
        __syncthreads();

        // ---- compute: 48 MFMA / wave ----
        short8 ah[4], al[4], bh[4], bl[4];
#pragma unroll
        for (int mi = 0; mi < 4; mi++) {
            ah[mi] = *(short8*)&As[(mi * 16 + lr) * 40 + lq * 8];
            al[mi] = *(short8*)&As[2560 + (mi * 16 + lr) * 40 + lq * 8];
        }
#pragma unroll
        for (int ni = 0; ni < 4; ni++) {
            bh[ni] = *(short8*)&Bs[(wv * 64 + ni * 16 + lr) * 40 + lq * 8];
            bl[ni] = *(short8*)&Bs[10240 + (wv * 64 + ni * 16 + lr) * 40 + lq * 8];
        }
#pragma unroll
        for (int mi = 0; mi < 4; mi++)
#pragma unroll
            for (int ni = 0; ni < 4; ni++) {
                acc[mi][ni] = __builtin_amdgcn_mfma_f32_16x16x32_bf16(ah[mi], bh[ni], acc[mi][ni], 0, 0, 0);
                acc[mi][ni] = __builtin_amdgcn_mfma_f32_16x16x32_bf16(ah[mi], bl[ni], acc[mi][ni], 0, 0, 0);
                acc[mi][ni] = __builtin_amdgcn_mfma_f32_16x16x32_bf16(al[mi], bh[ni], acc[mi][ni], 0, 0, 0);
            }
        __syncthreads();
    }

    // ---- epilogue ----
#pragma unroll
    for (int mi = 0; mi < 4; mi++)
#pragma unroll
        for (int ni = 0; ni < 4; ni++) {
            int col = n0 + wv * 64 + ni * 16 + lr;
#pragma unroll
            for (int r = 0; r < 4; r++) {
                int row = m0 + mi * 16 + lq * 4 + r;
                long o = (long)row * N + col;
                if (KSPLIT > 1) atomicAdd(&Cb[o], acc[mi][ni][r]);
                else            Cb[o] = acc[mi][ni][r] + bias[row];
            }
        }
}

// Softmax over batch axis (16)
__global__ void softmax_b_k(float* __restrict__ att, long NN)
{
    long idx = (long)blockIdx.x * 256 + threadIdx.x;
    if (idx >= NN) return;
    float r[16];
    float mx = -1e30f;
#pragma unroll
    for (int b = 0; b < 16; b++) {
        r[b] = att[(long)b * NN + idx];
        mx = fmaxf(mx, r[b]);
    }
    float s = 0.f;
#pragma unroll
    for (int b = 0; b < 16; b++) { r[b] = expf(r[b] - mx); s += r[b]; }
    float inv = 1.f / s;
#pragma unroll
    for (int b = 0; b < 16; b++) att[(long)b * NN + idx] = r[b] * inv;
}

// M[b][c][d] = softmax_c(gram_t) + softmax_c(gram_s)
__global__ void gram_sm_k(const float* __restrict__ gt, const float* __restrict__ gs,
                          float* __restrict__ Mo)
{
    int b = blockIdx.x;
    int d = blockIdx.y * 64 + threadIdx.x;
    const float* gtb = gt + (long)b * 65536;
    const float* gsb = gs + (long)b * 65536;
    float* mb = Mo + (long)b * 65536;
    float mt = -1e30f, ms = -1e30f;
    for (int c = 0; c < 256; c++) {
        mt = fmaxf(mt, gtb[c * 256 + d]);
        ms = fmaxf(ms, gsb[c * 256 + d]);
    }
    float st = 0.f, ss = 0.f;
    for (int c = 0; c < 256; c++) {
        st += expf(gtb[c * 256 + d] - mt);
        ss += expf(gsb[c * 256 + d] - ms);
    }
    float it = 1.f / st, is = 1.f / ss;
    for (int c = 0; c < 256; c++)
        mb[c * 256 + d] = expf(gtb[c * 256 + d] - mt) * it +
                          expf(gsb[c * 256 + d] - ms) * is;
}

__global__ void cast_out_k(const float* __restrict__ t, const float* __restrict__ s,
                           void* __restrict__ out, long nt, long ntot,
                           const int* __restrict__ flag)
{
    long idx = (long)blockIdx.x * 256 + threadIdx.x;
    if (idx >= ntot) return;
    float v = (idx < nt) ? t[idx] : s[idx - nt];
    if (*flag) ((float*)out)[idx] = v;
    else       ((bf16*)out)[idx] = __float2bfloat16(v);
}

// ---------------------------------------------------------------------------
extern "C" void kernel_launch(void* const* d_in, const int* in_sizes, int n_in,
                              void* d_out, int out_size, void* d_ws, size_t ws_size,
                              hipStream_t stream)
{
    const int B = 16, C = 256;
    const int Nt = 256, Ns = 1024;
    const long sXt = (long)C * Nt, sXs = (long)C * Ns;
    dim3 blk(256);

    float* ws = (float*)d_ws;
    int* flag = (int*)d_ws;
    long off = 16;
    auto alloc = [&](long n) { float* p = ws + off; off += n; return p; };

    float* xt32     = alloc((long)B * C * Nt);
    float* xs32     = alloc((long)B * C * Ns);   // -> out_s_f32
    float* Wf       = alloc(1470464);
    float* q_t      = alloc((long)B * 32 * Nt);
    float* k_t      = alloc((long)B * 32 * Nt);
    float* v_t      = alloc((long)B * C * Nt);
    float* q_s      = alloc((long)B * 32 * Ns);
    float* k_s      = alloc((long)B * 32 * Ns);
    float* v_s      = alloc((long)B * C * Ns);   // -> DCN prep region
    float* gram_t   = alloc((long)B * C * C);    // -> out_t_f32
    float* gram_s   = alloc((long)B * C * C);
    float* Mc       = alloc((long)B * C * C);
    float* att_t    = alloc((long)B * Nt * Nt);  // xtT early / attT_t late
    float* att_slab = alloc((long)B * Ns * 256); // xsT early / attT_slab late
    float* at       = alloc((long)B * C * Nt);
    float* asr      = alloc((long)B * C * Ns);
    float* oo_t     = alloc((long)B * 27 * Nt);
    float* oo_s     = alloc((long)B * 27 * Ns);

    float* out_t_f32 = gram_t;
    float* out_s_f32 = xs32;
    float* xtT       = att_t;
    float* xsT       = att_slab;
    // DCN prep inside v_s (dead after slab applies): bf16 planes + tables
    short* Wh_t = (short*)v_s;                    // 589824 shorts
    short* Wl_t = (short*)v_s + 589824;
    short* Wh_s = (short*)v_s + 2 * 589824;
    short* Wl_s = (short*)v_s + 3 * 589824;       // ends at 1179648 floats
    float* tb   = v_s + 1179648;
    float4* Tw_t = (float4*)tb;                   // 147456 f
    int4*   Ta_t = (int4*)(tb + 147456);
    float4* Tw_s = (float4*)(tb + 2 * 147456);    // 589824 f
    int4*   Ta_s = (int4*)(tb + 2 * 147456 + 589824);

    // ---- 0) detect + ingest ----
    detect_k<<<dim3(1), blk, 0, stream>>>((const unsigned short*)d_in[0], flag);
    long woff[22];
    {
        long acc = 0;
        for (int i = 2; i < 22; i++) { woff[i] = acc; acc += (in_sizes[i] + 7) & ~7L; }
    }
    IArgs ia;
    long tot = 0;
    auto seg = [&](int s, const void* src, float* dst, long n) {
        ia.src[s] = src; ia.dst[s] = dst; ia.start[s] = tot; tot += n;
    };
    seg(0, d_in[0], xt32, (long)B * C * Nt);
    seg(1, d_in[0], at,   (long)B * C * Nt);
    seg(2, d_in[1], xs32, (long)B * C * Ns);
    seg(3, d_in[1], asr,  (long)B * C * Ns);
    for (int i = 2; i < 22; i++) seg(2 + i, d_in[i], Wf + woff[i], in_sizes[i]);
    ia.start[NSEG] = tot;
    ingest_all_k<<<dim3((unsigned)((tot + 255) / 256)), blk, 0, stream>>>(ia, flag);

    const float *tq_w = Wf + woff[2],  *tq_b = Wf + woff[3];
    const float *tk_w = Wf + woff[4],  *tk_b = Wf + woff[5];
    const float *tv_w = Wf + woff[6],  *tv_b = Wf + woff[7];
    const float *sq_w = Wf + woff[8],  *sq_b = Wf + woff[9];
    const float *sk_w = Wf + woff[10], *sk_b = Wf + woff[11];
    const float *sv_w = Wf + woff[12], *sv_b = Wf + woff[13];
    const float *t_off_w = Wf + woff[14], *t_off_b = Wf + woff[15];
    const float *t_dcn_w = Wf + woff[16], *t_dcn_b = Wf + woff[17];
    const float *s_off_w = Wf + woff[18], *s_off_b = Wf + woff[19];
    const float *s_dcn_w = Wf + woff[20], *s_dcn_b = Wf + woff[21];

    // ---- 1) transposes + prefills ----
    tr_k<<<dim3(Nt / 32, 8, B), dim3(32, 8), 0, stream>>>(xt32, xtT, Nt);
    tr_k<<<dim3(Ns / 32, 8, B), dim3(32, 8), 0, stream>>>(xs32, xsT, Ns);
    fill_k<<<dim3((2 * B * C * C) / 256), blk, 0, stream>>>(gram_t, nullptr, 1, 1, 2L * B * C * C);
    fill_k<<<dim3((B * 27 * Nt + 255) / 256), blk, 0, stream>>>(oo_t, t_off_b, 27L * Nt, Nt, (long)B * 27 * Nt);
    fill_k<<<dim3((B * 27 * Ns + 255) / 256), blk, 0, stream>>>(oo_s, s_off_b, 27L * Ns, Ns, (long)B * 27 * Ns);

    // ---- 2) q,k,v projections (B = x^T, BMODE1, PREC2) ----
    mgemm<false, 1, false, true, 2, 1><<<dim3(Nt / 64, 1, B), blk, 0, stream>>>(
        tq_w, 256, 1, 0, xtT, 256, sXt, q_t, Nt, (long)32 * Nt, tq_b, 32, Nt, 256, 0, 0);
    mgemm<false, 1, false, true, 2, 1><<<dim3(Nt / 64, 1, B), blk, 0, stream>>>(
        tk_w, 256, 1, 0, xtT, 256, sXt, k_t, Nt, (long)32 * Nt, tk_b, 32, Nt, 256, 0, 0);
    mgemm<false, 1, false, true, 2, 1><<<dim3(Nt / 64, 4, B), blk, 0, stream>>>(
        tv_w, 256, 1, 0, xtT, 256, sXt, v_t, Nt, sXt, tv_b, 256, Nt, 256, 0, 0);
    mgemm<false, 1, false, true, 2, 1><<<dim3(Ns / 64, 1, B), blk, 0, stream>>>(
        sq_w, 256, 1, 0, xsT, 256, sXs, q_s, Ns, (long)32 * Ns, sq_b, 32, Ns, 256, 0, 0);
    mgemm<false, 1, false, true, 2, 1><<<dim3(Ns / 64, 1, B), blk, 0, stream>>>(
        sk_w, 256, 1, 0, xsT, 256, sXs, k_s, Ns, (long)32 * Ns, sk_b, 32, Ns, 256, 0, 0);
    mgemm<false, 1, false, true, 2, 1><<<dim3(Ns / 64, 4, B), blk, 0, stream>>>(
        sv_w, 256, 1, 0, xsT, 256, sXs, v_s, Ns, sXs, sv_b, 256, Ns, 256, 0, 0);

    // ---- 3) gram matrices (BMODE1, K-split 4) ----
    mgemm<false, 1, false, false, 1, 4><<<dim3(4, 16, B), blk, 0, stream>>>(
        xt32, Nt, 1, sXt, xt32, Nt, sXt, gram_t, 256, (long)C * C, nullptr, 256, 256, Nt, 0, 0);
    mgemm<false, 1, false, false, 1, 4><<<dim3(4, 16, B), blk, 0, stream>>>(
        xs32, Ns, 1, sXs, xs32, Ns, sXs, gram_s, 256, (long)C * C, nullptr, 256, 256, Ns, 0, 0);

    // ---- 4) M ----
    gram_sm_k<<<dim3(B, 4), dim3(64), 0, stream>>>(gram_t, gram_s, Mc);

    // ---- 5) channel attention (B = x^T, BMODE1) ----
    mgemm<false, 1, true, false, 2, 2><<<dim3(Nt / 64, 8, B), blk, 0, stream>>>(
        Mc, 256, 1, (long)C * C, xtT, 256, sXt, at, Nt, sXt, nullptr, 256, Nt, 256, 0, 0);
    mgemm<false, 1, true, false, 2, 1><<<dim3(Ns / 64, 4, B), blk, 0, stream>>>(
        Mc, 256, 1, (long)C * C, xsT, 256, sXs, asr, Ns, sXs, nullptr, 256, Ns, 256, 0, 0);

    // ---- 6) template spatial attention (transposed logits) ----
    mgemm<true, 0, false, false, 2, 1><<<dim3(4, 4, B), blk, 0, stream>>>(
        k_t, Nt, 1, (long)32 * Nt, q_t, Nt, (long)32 * Nt, att_t, Nt, (long)Nt * Nt,
        nullptr, Nt, Nt, 32, 0, 0);
    softmax_b_k<<<dim3((Nt * Nt) / 256), blk, 0, stream>>>(att_t, (long)Nt * Nt);
    mgemm<false, 1, true, false, 2, 2><<<dim3(Nt / 64, 8, B), blk, 0, stream>>>(
        v_t, Nt, 1, sXt, att_t, Nt, (long)Nt * Nt, at, Nt, sXt, nullptr, 256, Nt, Nt, 0, 0);

    // ---- 7) search spatial attention, 4 m-slabs (transposed logits) ----
    for (int m0s = 0; m0s < Ns; m0s += 256) {
        mgemm<true, 0, false, false, 2, 1><<<dim3(Ns / 64, 4, B), blk, 0, stream>>>(
            k_s + m0s, Ns, 1, (long)32 * Ns, q_s, Ns, (long)32 * Ns,
            att_slab, Ns, (long)256 * Ns, nullptr, 256, Ns, 32, 0, 0);
        softmax_b_k<<<dim3((256 * Ns) / 256), blk, 0, stream>>>(att_slab, (long)256 * Ns);
        mgemm<false, 1, true, false, 2, 4><<<dim3(4, 16, B), blk, 0, stream>>>(
            v_s, Ns, 1, sXs, att_slab, Ns, (long)256 * Ns,
            asr + m0s, Ns, sXs, nullptr, 256, 256, Ns, 0, 0);
    }

    // ---- 8) offset convs (im2col, K-split 4, bias prefilled) ----
    mgemm<false, 3, false, false, 2, 4><<<dim3(Nt / 64, 4, B), blk, 0, stream>>>(
        t_off_w, 2304, 1, 0, at, Nt, sXt, oo_t, Nt, (long)27 * Nt,
        nullptr, 27, Nt, 2304, 16, 4);
    mgemm<false, 3, false, false, 2, 4><<<dim3(Ns / 64, 4, B), blk, 0, stream>>>(
        s_off_w, 2304, 1, 0, asr, Ns, sXs, oo_s, Ns, (long)27 * Ns,
        nullptr, 27, Ns, 2304, 32, 5);

    // ---- 9) DCN prep (v_s region now dead) ----
    wre2_k<<<dim3((2304 * 256) / 256), blk, 0, stream>>>(t_dcn_w, Wh_t, Wl_t);
    wre2_k<<<dim3((2304 * 256) / 256), blk, 0, stream>>>(s_dcn_w, Wh_s, Wl_s);
    dcnw_k<<<dim3((B * 9 * Nt) / 256), blk, 0, stream>>>(oo_t, Tw_t, Ta_t, Nt, 16, 16);
    dcnw_k<<<dim3((B * 9 * Ns) / 256), blk, 0, stream>>>(oo_s, Tw_s, Ta_s, Ns, 32, 32);

    // ---- 10) fused deformable convs (v2) ----
    fill_k<<<dim3((B * C * Nt + 255) / 256), blk, 0, stream>>>(
        out_t_f32, t_dcn_b, (long)C * Nt, Nt, (long)B * C * Nt);
    dcn2_k<2, false><<<dim3(1, 8, 16), blk, 0, stream>>>(
        Wh_t, Wl_t, Tw_t, Ta_t, at, t_dcn_b, out_t_f32, Nt);
    dcn2_k<1, true><<<dim3(256), blk, 0, stream>>>(
        Wh_s, Wl_s, Tw_s, Ta_s, asr, s_dcn_b, out_s_f32, Ns);

    // ---- 11) emit output ----
    long nt = (long)B * C * Nt;
    long ntot = nt + (long)B * C * Ns;
    cast_out_k<<<dim3((unsigned)((ntot + 255) / 256)), blk, 0, stream>>>(
        out_t_f32, out_s_f32, d_out, nt, ntot, flag);
}

// Round 10
// 1264.606 us; speedup vs baseline: 1.1493x; 1.1493x over previous
//
#include <hip/hip_runtime.h>
#include <hip/hip_bf16.h>

typedef __hip_bfloat16 bf16;
typedef __attribute__((ext_vector_type(8))) short short8;
typedef __attribute__((ext_vector_type(4))) float f32x4;

__device__ __forceinline__ short f2b(float v)
{
    union { bf16 b; short s; } u;
    u.b = __float2bfloat16(v);
    return u.s;
}
__device__ __forceinline__ float b2f(short s)
{
    union { short s; bf16 b; } u;
    u.s = s;
    return __bfloat162float(u.b);
}
__device__ __forceinline__ void splt(float v, short& hi, short& lo)
{
    hi = f2b(v);
    lo = f2b(v - b2f(hi));
}
__device__ __forceinline__ int bsw(int row, int g)
{
    return row * 40 + (((g + (row >> 3)) & 3) << 3);
}

// ---------------------------------------------------------------------------
// Dtype detector (validated r2): flag=1 -> fp32 storage, 0 -> bf16.
// ---------------------------------------------------------------------------
__global__ void detect_k(const unsigned short* __restrict__ p, int* __restrict__ flag)
{
    __shared__ int cnt;
    if (threadIdx.x == 0) cnt = 0;
    __syncthreads();
    int bad = 0;
    for (int i = threadIdx.x; i < 4096; i += 256) {
        unsigned short u = p[2 * i];
        int e = (u >> 7) & 0xFF;
        if (e != 0 && (e < 100 || e > 140)) bad++;
    }
    atomicAdd(&cnt, bad);
    __syncthreads();
    if (threadIdx.x == 0) *flag = (cnt > 1024) ? 1 : 0;
}

// ---------------------------------------------------------------------------
// Fused ingest (validated r5)
// ---------------------------------------------------------------------------
#define NSEG 24
struct IArgs {
    const void* src[NSEG];
    float* dst[NSEG];
    long start[NSEG + 1];
};

__global__ void ingest_all_k(IArgs a, const int* __restrict__ flag)
{
    long i = (long)blockIdx.x * 256 + threadIdx.x;
    if (i >= a.start[NSEG]) return;
    int s = 0;
#pragma unroll
    for (int j = 1; j < NSEG; j++) s += (i >= a.start[j]) ? 1 : 0;
    long idx = i - a.start[s];
    float v;
    if (*flag) v = ((const float*)a.src[s])[idx];
    else       v = __bfloat162float(((const bf16*)a.src[s])[idx]);
    a.dst[s][idx] = v;
}

// C[b][m][n] = bias[m] (or 0).  total = B*MN.
__global__ void fill_k(float* __restrict__ C, const float* __restrict__ bias,
                       long MN, int Nn, long total)
{
    long i = (long)blockIdx.x * 256 + threadIdx.x;
    if (i >= total) return;
    float v = 0.f;
    if (bias) {
        long r = i % MN;
        v = bias[(int)(r / Nn)];
    }
    C[i] = v;
}

// Tiled transpose: X[b][c][n] -> XT[b][n][c].  C=256. grid (N/32, 8, B), blk (32,8)
__global__ void tr_k(const float* __restrict__ X, float* __restrict__ XT, int N)
{
    __shared__ float t[32][33];
    int b = blockIdx.z, n0 = blockIdx.x * 32, c0 = blockIdx.y * 32;
    const float* Xb = X + (long)b * 256 * N;
    float* Tb = XT + (long)b * 256 * N;
    int tx = threadIdx.x, ty = threadIdx.y;
#pragma unroll
    for (int i = 0; i < 4; i++)
        t[ty + 8 * i][tx] = Xb[(long)(c0 + ty + 8 * i) * N + n0 + tx];
    __syncthreads();
#pragma unroll
    for (int i = 0; i < 4; i++)
        Tb[(long)(n0 + ty + 8 * i) * 256 + c0 + tx] = t[tx][ty + 8 * i];
}

// ---------------------------------------------------------------------------
// MFMA bf16 GEMM (validated r8/r9) — non-DCN ops.
// ---------------------------------------------------------------------------
template <bool TRA, int BMODE, bool ACCUM, bool BIAS, int PREC, int KSPLIT>
__launch_bounds__(256)
__global__ void mgemm(const float* __restrict__ A, int lda, int ksA, long sA,
                      const void* __restrict__ Bsrc, int ldb, long sB,
                      float* __restrict__ C, int ldc, long sC,
                      const float* __restrict__ bias,
                      int M, int N, int K, int H, int wsh)
{
    __shared__ short As[PREC * 2560];
    __shared__ short Bs[PREC * 2560];

    const int bz = blockIdx.z;
    const float* Ab = A + (long)bz * sA;
    float* Cb = C + (long)bz * sC;
    const int mt = blockIdx.y / KSPLIT, ch = blockIdx.y % KSPLIT;
    const int m0 = mt * 64, n0 = blockIdx.x * 64;
    const int kchunk = K / KSPLIT;
    const int kbeg = ch * kchunk, kend = kbeg + kchunk;
    const int tid = threadIdx.x;

    f32x4 acc[2][2];
#pragma unroll
    for (int i = 0; i < 2; i++)
#pragma unroll
        for (int j = 0; j < 2; j++) acc[i][j] = (f32x4){0.f, 0.f, 0.f, 0.f};

    const int lane = tid & 63, wv = tid >> 6;
    const int moff = (wv & 1) * 32, noff = (wv >> 1) * 32;
    const int lr = lane & 15, lq = lane >> 4;
    const int mm = tid >> 2, kk0 = (tid & 3) * 8;
    const int nn = tid & 63, kg = tid >> 6;

    for (int k0 = kbeg; k0 < kend; k0 += 32) {
        // ---- stage A ----
        {
            float vv[8];
            if (m0 + mm < M) {
                if (!TRA) {
                    if (ksA == 1) {
                        const float4* s4 = (const float4*)(Ab + (long)(m0 + mm) * lda + k0 + kk0);
                        float4 v0 = s4[0], v1 = s4[1];
                        vv[0] = v0.x; vv[1] = v0.y; vv[2] = v0.z; vv[3] = v0.w;
                        vv[4] = v1.x; vv[5] = v1.y; vv[6] = v1.z; vv[7] = v1.w;
                    } else {
                        const float* s = Ab + (long)(m0 + mm) * lda + (long)(k0 + kk0) * ksA;
#pragma unroll
                        for (int j = 0; j < 8; j++) vv[j] = s[(long)j * ksA];
                    }
                } else {
#pragma unroll
                    for (int j = 0; j < 8; j++)
                        vv[j] = Ab[(long)(k0 + kk0 + j) * lda + m0 + mm];
                }
            } else {
#pragma unroll
                for (int j = 0; j < 8; j++) vv[j] = 0.f;
            }
            short8 hi, lo;
#pragma unroll
            for (int j = 0; j < 8; j++) { short h, l; splt(vv[j], h, l); hi[j] = h; lo[j] = l; }
            *(short8*)&As[mm * 40 + kk0] = hi;
            if (PREC == 2) *(short8*)&As[2560 + mm * 40 + kk0] = lo;
        }

        // ---- stage B ----
        if (BMODE == 1) {
            const float4* s4 = (const float4*)((const float*)Bsrc + (long)bz * sB +
                                               (long)(n0 + mm) * ldb + k0 + kk0);
            float4 v0 = s4[0], v1 = s4[1];
            float vv[8] = {v0.x, v0.y, v0.z, v0.w, v1.x, v1.y, v1.z, v1.w};
            short8 hi, lo;
#pragma unroll
            for (int j = 0; j < 8; j++) { short h, l; splt(vv[j], h, l); hi[j] = h; lo[j] = l; }
            int o = bsw(mm, tid & 3);
            *(short8*)&Bs[o] = hi;
            if (PREC == 2) *(short8*)&Bs[2560 + o] = lo;
        } else {
            float vv[8];
            if (BMODE == 0) {
#pragma unroll
                for (int j = 0; j < 8; j++)
                    vv[j] = ((const float*)Bsrc)[(long)bz * sB + (long)(k0 + kg * 8 + j) * ldb + n0 + nn];
            } else {  // BMODE 3: im2col
                int W = 1 << wsh;
                int n = n0 + nn;
                int hbase = n >> wsh, wbase = n & (W - 1);
#pragma unroll
                for (int j = 0; j < 8; j++) {
                    int kc = k0 + kg * 8 + j;
                    int c = kc / 9, tap = kc - 9 * c;
                    int h = hbase + tap / 3 - 1, w = wbase + tap % 3 - 1;
                    vv[j] = (h >= 0 && h < H && w >= 0 && w < W)
                          ? ((const float*)Bsrc)[(long)bz * sB + (long)c * ldb + (h << wsh) + w]
                          : 0.f;
                }
            }
            short8 hi, lo;
#pragma unroll
            for (int j = 0; j < 8; j++) { short h, l; splt(vv[j], h, l); hi[j] = h; lo[j] = l; }
            int o = bsw(nn, kg);
            *(short8*)&Bs[o] = hi;
            if (PREC == 2) *(short8*)&Bs[2560 + o] = lo;
        }
        __syncthreads();

        // ---- compute ----
        int rb0 = noff + lr, rb1 = noff + 16 + lr;
        short8 a0h = *(short8*)&As[(moff + lr) * 40 + lq * 8];
        short8 a1h = *(short8*)&As[(moff + 16 + lr) * 40 + lq * 8];
        short8 b0h = *(short8*)&Bs[bsw(rb0, lq)];
        short8 b1h = *(short8*)&Bs[bsw(rb1, lq)];
        acc[0][0] = __builtin_amdgcn_mfma_f32_16x16x32_bf16(a0h, b0h, acc[0][0], 0, 0, 0);
        acc[0][1] = __builtin_amdgcn_mfma_f32_16x16x32_bf16(a0h, b1h, acc[0][1], 0, 0, 0);
        acc[1][0] = __builtin_amdgcn_mfma_f32_16x16x32_bf16(a1h, b0h, acc[1][0], 0, 0, 0);
        acc[1][1] = __builtin_amdgcn_mfma_f32_16x16x32_bf16(a1h, b1h, acc[1][1], 0, 0, 0);
        if (PREC == 2) {
            short8 a0l = *(short8*)&As[2560 + (moff + lr) * 40 + lq * 8];
            short8 a1l = *(short8*)&As[2560 + (moff + 16 + lr) * 40 + lq * 8];
            short8 b0l = *(short8*)&Bs[2560 + bsw(rb0, lq)];
            short8 b1l = *(short8*)&Bs[2560 + bsw(rb1, lq)];
            acc[0][0] = __builtin_amdgcn_mfma_f32_16x16x32_bf16(a0h, b0l, acc[0][0], 0, 0, 0);
            acc[0][1] = __builtin_amdgcn_mfma_f32_16x16x32_bf16(a0h, b1l, acc[0][1], 0, 0, 0);
            acc[1][0] = __builtin_amdgcn_mfma_f32_16x16x32_bf16(a1h, b0l, acc[1][0], 0, 0, 0);
            acc[1][1] = __builtin_amdgcn_mfma_f32_16x16x32_bf16(a1h, b1l, acc[1][1], 0, 0, 0);
            acc[0][0] = __builtin_amdgcn_mfma_f32_16x16x32_bf16(a0l, b0h, acc[0][0], 0, 0, 0);
            acc[0][1] = __builtin_amdgcn_mfma_f32_16x16x32_bf16(a0l, b1h, acc[0][1], 0, 0, 0);
            acc[1][0] = __builtin_amdgcn_mfma_f32_16x16x32_bf16(a1l, b0h, acc[1][0], 0, 0, 0);
            acc[1][1] = __builtin_amdgcn_mfma_f32_16x16x32_bf16(a1l, b1h, acc[1][1], 0, 0, 0);
        }
        __syncthreads();
    }

    // ---- epilogue ----
#pragma unroll
    for (int mi = 0; mi < 2; mi++)
#pragma unroll
        for (int ni = 0; ni < 2; ni++) {
            int col = n0 + noff + ni * 16 + lr;
#pragma unroll
            for (int r = 0; r < 4; r++) {
                int row = m0 + moff + mi * 16 + lq * 4 + r;
                if (row < M) {
                    long o = (long)row * ldc + col;
                    float v = acc[mi][ni][r];
                    if (KSPLIT > 1) {
                        atomicAdd(&Cb[o], v);
                    } else {
                        if (BIAS) v += bias[row];
                        if (ACCUM) v += Cb[o];
                        Cb[o] = v;
                    }
                }
            }
        }
}

// ---------------------------------------------------------------------------
// DCN bilinear corner tables
// ---------------------------------------------------------------------------
__global__ void dcnw_k(const float* __restrict__ OO, float4* __restrict__ Tw,
                       int4* __restrict__ Ta, int N, int H, int W)
{
    long idx = (long)blockIdx.x * 256 + threadIdx.x;
    if (idx >= (long)16 * 9 * N) return;
    int b = (int)(idx / (9 * N));
    int r = (int)(idx % (9 * N));
    int tap = r / N, p = r % N;
    int h = p / W, w = p % W;
    const float* oob = OO + (long)b * 27 * N;
    float oy = oob[(2 * tap) * N + p];
    float ox = oob[(2 * tap + 1) * N + p];
    float mz = oob[(18 + tap) * N + p];
    float mask = 1.f / (1.f + expf(-mz));
    float y = (float)(h - 1 + tap / 3) + oy;
    float x = (float)(w - 1 + tap % 3) + ox;
    float y0 = floorf(y), x0 = floorf(x);
    float wy = y - y0, wx = x - x0;
    float ys[2] = {y0, y0 + 1.f};
    float xs[2] = {x0, x0 + 1.f};
    float wys[2] = {1.f - wy, wy};
    float wxs[2] = {1.f - wx, wx};
    float wv[4]; int av[4];
#pragma unroll
    for (int iy = 0; iy < 2; iy++)
#pragma unroll
        for (int ix = 0; ix < 2; ix++) {
            float yy = ys[iy], xx = xs[ix];
            bool valid = (yy >= 0.f) && (yy <= (float)(H - 1)) &&
                         (xx >= 0.f) && (xx <= (float)(W - 1));
            wv[iy * 2 + ix] = valid ? wys[iy] * wxs[ix] * mask : 0.f;
            int yc = (int)fminf(fmaxf(yy, 0.f), (float)(H - 1));
            int xc = (int)fminf(fmaxf(xx, 0.f), (float)(W - 1));
            av[iy * 2 + ix] = yc * W + xc;
        }
    Tw[idx] = (float4){wv[0], wv[1], wv[2], wv[3]};
    Ta[idx] = (int4){av[0], av[1], av[2], av[3]};
}

// DCN weight prepack to split-bf16 planes: Wh/Wl[o][tap*256+c]
__global__ void wre2_k(const float* __restrict__ W, short* __restrict__ Wh,
                       short* __restrict__ Wl)
{
    long idx = (long)blockIdx.x * 256 + threadIdx.x;
    if (idx >= 2304L * 256) return;
    int o = (int)(idx / 2304);
    int k = (int)(idx % 2304);
    int tap = k >> 8, c = k & 255;
    short h, l;
    splt(W[((long)o * 256 + c) * 9 + tap], h, l);
    Wh[idx] = h;
    Wl[idx] = l;
}

// ---------------------------------------------------------------------------
// Fused deformable conv v3: tile M=64 x N=256, K split KSPLIT ways.
// Grid: 1-D, 8 XCD groups x (2 bz x 4 mt x NT x KSPLIT).  3 blocks/CU
// co-resident (LDS 50KB) so inter-block overlap hides gather latency.
// atomicAdd epilogue into bias-prefilled C.
// ---------------------------------------------------------------------------
template <int KSPLIT, int NT>
__launch_bounds__(256)
__global__ void dcn2_k(const short* __restrict__ Wh, const short* __restrict__ Wl,
                       const float4* __restrict__ Tw, const int4* __restrict__ Ta,
                       const float* __restrict__ X, float* __restrict__ C, int N)
{
    __shared__ short As[2 * 2560];   // [part][64][40]
    __shared__ short Bs[2 * 10240];  // [part][256][40] swizzled

    const int per = 4 * NT * KSPLIT;          // tiles per image
    int bid = blockIdx.x;
    int g = bid & 7, r = bid >> 3;            // XCD group, local idx
    int bz = g * 2 + (r >= per ? 1 : 0);
    int t2 = r % per;
    int mt = t2 / (NT * KSPLIT);
    int t3 = t2 % (NT * KSPLIT);
    int nt = t3 / KSPLIT, ch = t3 % KSPLIT;
    const int m0 = mt * 64, n0 = nt * 256;

    const int tid = threadIdx.x;
    const int lane = tid & 63, wv = tid >> 6;
    const int lr = lane & 15, lq = lane >> 4;
    const int arow = tid >> 2, akg = tid & 3;
    const float* Xb = X + (long)bz * 256 * N;
    float* Cb = C + (long)bz * 256 * N;

    f32x4 acc[4][4];
#pragma unroll
    for (int i = 0; i < 4; i++)
#pragma unroll
        for (int j = 0; j < 4; j++) acc[i][j] = (f32x4){0.f, 0.f, 0.f, 0.f};

    const int itc = 72 / KSPLIT;
    for (int kt = ch * itc; kt < ch * itc + itc; kt++) {
        int tap = kt >> 3, c0 = (kt & 7) * 32;
        // ---- stage A: bf16 planes, direct short8 copy ----
        {
            long o = (long)(m0 + arow) * 2304 + tap * 256 + c0 + akg * 8;
            *(short8*)&As[arow * 40 + akg * 8] = *(const short8*)&Wh[o];
            *(short8*)&As[2560 + arow * 40 + akg * 8] = *(const short8*)&Wl[o];
        }
        // ---- stage B: sample 32 channels for this thread's column ----
        {
            long ti = (long)(bz * 9 + tap) * N + n0 + tid;
            float4 w4 = Tw[ti];
            int4 a4 = Ta[ti];
            short8 h8[4], l8[4];
#pragma unroll
            for (int q = 0; q < 4; q++)
#pragma unroll
                for (int j = 0; j < 8; j++) {
                    const float* rr = Xb + (long)(c0 + q * 8 + j) * N;
                    float v = w4.x * rr[a4.x] + w4.y * rr[a4.y] +
                              w4.z * rr[a4.z] + w4.w * rr[a4.w];
                    short hh, ll; splt(v, hh, ll);
                    h8[q][j] = hh; l8[q][j] = ll;
                }
#pragma unroll
            for (int q = 0; q < 4; q++) {
                int o = bsw(tid, q);
                *(short8*)&Bs[o] = h8[q];
                *(short8*)&Bs[10240 + o] = l8[q];
            }
        }
        __syncthreads();

        // ---- compute: 48 MFMA / wave ----
        short8 ah[4], al[4], bh[4], bl[4];
#pragma unroll
        for (int mi = 0; mi < 4; mi++) {
            ah[mi] = *(short8*)&As[(mi * 16 + lr) * 40 + lq * 8];
            al[mi] = *(short8*)&As[2560 + (mi * 16 + lr) * 40 + lq * 8];
        }
#pragma unroll
        for (int ni = 0; ni < 4; ni++) {
            int o = bsw(wv * 64 + ni * 16 + lr, lq);
            bh[ni] = *(short8*)&Bs[o];
            bl[ni] = *(short8*)&Bs[10240 + o];
        }
#pragma unroll
        for (int mi = 0; mi < 4; mi++)
#pragma unroll
            for (int ni = 0; ni < 4; ni++) {
                acc[mi][ni] = __builtin_amdgcn_mfma_f32_16x16x32_bf16(ah[mi], bh[ni], acc[mi][ni], 0, 0, 0);
                acc[mi][ni] = __builtin_amdgcn_mfma_f32_16x16x32_bf16(ah[mi], bl[ni], acc[mi][ni], 0, 0, 0);
                acc[mi][ni] = __builtin_amdgcn_mfma_f32_16x16x32_bf16(al[mi], bh[ni], acc[mi][ni], 0, 0, 0);
            }
        __syncthreads();
    }

    // ---- epilogue: atomic accumulate into bias-prefilled C ----
#pragma unroll
    for (int mi = 0; mi < 4; mi++)
#pragma unroll
        for (int ni = 0; ni < 4; ni++) {
            int col = n0 + wv * 64 + ni * 16 + lr;
#pragma unroll
            for (int r2 = 0; r2 < 4; r2++) {
                int row = m0 + mi * 16 + lq * 4 + r2;
                atomicAdd(&Cb[(long)row * N + col], acc[mi][ni][r2]);
            }
        }
}

// Softmax over batch axis (16)
__global__ void softmax_b_k(float* __restrict__ att, long NN)
{
    long idx = (long)blockIdx.x * 256 + threadIdx.x;
    if (idx >= NN) return;
    float r[16];
    float mx = -1e30f;
#pragma unroll
    for (int b = 0; b < 16; b++) {
        r[b] = att[(long)b * NN + idx];
        mx = fmaxf(mx, r[b]);
    }
    float s = 0.f;
#pragma unroll
    for (int b = 0; b < 16; b++) { r[b] = expf(r[b] - mx); s += r[b]; }
    float inv = 1.f / s;
#pragma unroll
    for (int b = 0; b < 16; b++) att[(long)b * NN + idx] = r[b] * inv;
}

// M[b][c][d] = softmax_c(gram_t) + softmax_c(gram_s)
__global__ void gram_sm_k(const float* __restrict__ gt, const float* __restrict__ gs,
                          float* __restrict__ Mo)
{
    int b = blockIdx.x;
    int d = blockIdx.y * 64 + threadIdx.x;
    const float* gtb = gt + (long)b * 65536;
    const float* gsb = gs + (long)b * 65536;
    float* mb = Mo + (long)b * 65536;
    float mt = -1e30f, ms = -1e30f;
    for (int c = 0; c < 256; c++) {
        mt = fmaxf(mt, gtb[c * 256 + d]);
        ms = fmaxf(ms, gsb[c * 256 + d]);
    }
    float st = 0.f, ss = 0.f;
    for (int c = 0; c < 256; c++) {
        st += expf(gtb[c * 256 + d] - mt);
        ss += expf(gsb[c * 256 + d] - ms);
    }
    float it = 1.f / st, is = 1.f / ss;
    for (int c = 0; c < 256; c++)
        mb[c * 256 + d] = expf(gtb[c * 256 + d] - mt) * it +
                          expf(gsb[c * 256 + d] - ms) * is;
}

__global__ void cast_out_k(const float* __restrict__ t, const float* __restrict__ s,
                           void* __restrict__ out, long nt, long ntot,
                           const int* __restrict__ flag)
{
    long idx = (long)blockIdx.x * 256 + threadIdx.x;
    if (idx >= ntot) return;
    float v = (idx < nt) ? t[idx] : s[idx - nt];
    if (*flag) ((float*)out)[idx] = v;
    else       ((bf16*)out)[idx] = __float2bfloat16(v);
}

// ---------------------------------------------------------------------------
extern "C" void kernel_launch(void* const* d_in, const int* in_sizes, int n_in,
                              void* d_out, int out_size, void* d_ws, size_t ws_size,
                              hipStream_t stream)
{
    const int B = 16, C = 256;
    const int Nt = 256, Ns = 1024;
    const long sXt = (long)C * Nt, sXs = (long)C * Ns;
    dim3 blk(256);

    float* ws = (float*)d_ws;
    int* flag = (int*)d_ws;
    long off = 16;
    auto alloc = [&](long n) { float* p = ws + off; off += n; return p; };

    float* xt32     = alloc((long)B * C * Nt);
    float* xs32     = alloc((long)B * C * Ns);   // -> out_s_f32
    float* Wf       = alloc(1470464);
    float* q_t      = alloc((long)B * 32 * Nt);
    float* k_t      = alloc((long)B * 32 * Nt);
    float* v_t      = alloc((long)B * C * Nt);
    float* q_s      = alloc((long)B * 32 * Ns);
    float* k_s      = alloc((long)B * 32 * Ns);
    float* v_s      = alloc((long)B * C * Ns);   // -> DCN prep region
    float* gram_t   = alloc((long)B * C * C);    // -> out_t_f32
    float* gram_s   = alloc((long)B * C * C);
    float* Mc       = alloc((long)B * C * C);
    float* att_t    = alloc((long)B * Nt * Nt);  // xtT early / attT_t late
    float* att_slab = alloc((long)B * Ns * 256); // xsT early / attT_slab late
    float* at       = alloc((long)B * C * Nt);
    float* asr      = alloc((long)B * C * Ns);
    float* oo_t     = alloc((long)B * 27 * Nt);
    float* oo_s     = alloc((long)B * 27 * Ns);

    float* out_t_f32 = gram_t;
    float* out_s_f32 = xs32;
    float* xtT       = att_t;
    float* xsT       = att_slab;
    short* Wh_t = (short*)v_s;
    short* Wl_t = (short*)v_s + 589824;
    short* Wh_s = (short*)v_s + 2 * 589824;
    short* Wl_s = (short*)v_s + 3 * 589824;
    float* tb   = v_s + 1179648;
    float4* Tw_t = (float4*)tb;
    int4*   Ta_t = (int4*)(tb + 147456);
    float4* Tw_s = (float4*)(tb + 2 * 147456);
    int4*   Ta_s = (int4*)(tb + 2 * 147456 + 589824);

    // ---- 0) detect + ingest ----
    detect_k<<<dim3(1), blk, 0, stream>>>((const unsigned short*)d_in[0], flag);
    long woff[22];
    {
        long acc = 0;
        for (int i = 2; i < 22; i++) { woff[i] = acc; acc += (in_sizes[i] + 7) & ~7L; }
    }
    IArgs ia;
    long tot = 0;
    auto seg = [&](int s, const void* src, float* dst, long n) {
        ia.src[s] = src; ia.dst[s] = dst; ia.start[s] = tot; tot += n;
    };
    seg(0, d_in[0], xt32, (long)B * C * Nt);
    seg(1, d_in[0], at,   (long)B * C * Nt);
    seg(2, d_in[1], xs32, (long)B * C * Ns);
    seg(3, d_in[1], asr,  (long)B * C * Ns);
    for (int i = 2; i < 22; i++) seg(2 + i, d_in[i], Wf + woff[i], in_sizes[i]);
    ia.start[NSEG] = tot;
    ingest_all_k<<<dim3((unsigned)((tot + 255) / 256)), blk, 0, stream>>>(ia, flag);

    const float *tq_w = Wf + woff[2],  *tq_b = Wf + woff[3];
    const float *tk_w = Wf + woff[4],  *tk_b = Wf + woff[5];
    const float *tv_w = Wf + woff[6],  *tv_b = Wf + woff[7];
    const float *sq_w = Wf + woff[8],  *sq_b = Wf + woff[9];
    const float *sk_w = Wf + woff[10], *sk_b = Wf + woff[11];
    const float *sv_w = Wf + woff[12], *sv_b = Wf + woff[13];
    const float *t_off_w = Wf + woff[14], *t_off_b = Wf + woff[15];
    const float *t_dcn_w = Wf + woff[16], *t_dcn_b = Wf + woff[17];
    const float *s_off_w = Wf + woff[18], *s_off_b = Wf + woff[19];
    const float *s_dcn_w = Wf + woff[20], *s_dcn_b = Wf + woff[21];

    // ---- 1) transposes + prefills ----
    tr_k<<<dim3(Nt / 32, 8, B), dim3(32, 8), 0, stream>>>(xt32, xtT, Nt);
    tr_k<<<dim3(Ns / 32, 8, B), dim3(32, 8), 0, stream>>>(xs32, xsT, Ns);
    fill_k<<<dim3((2 * B * C * C) / 256), blk, 0, stream>>>(gram_t, nullptr, 1, 1, 2L * B * C * C);
    fill_k<<<dim3((B * 27 * Nt + 255) / 256), blk, 0, stream>>>(oo_t, t_off_b, 27L * Nt, Nt, (long)B * 27 * Nt);
    fill_k<<<dim3((B * 27 * Ns + 255) / 256), blk, 0, stream>>>(oo_s, s_off_b, 27L * Ns, Ns, (long)B * 27 * Ns);

    // ---- 2) q,k,v projections (B = x^T, BMODE1, PREC2) ----
    mgemm<false, 1, false, true, 2, 1><<<dim3(Nt / 64, 1, B), blk, 0, stream>>>(
        tq_w, 256, 1, 0, xtT, 256, sXt, q_t, Nt, (long)32 * Nt, tq_b, 32, Nt, 256, 0, 0);
    mgemm<false, 1, false, true, 2, 1><<<dim3(Nt / 64, 1, B), blk, 0, stream>>>(
        tk_w, 256, 1, 0, xtT, 256, sXt, k_t, Nt, (long)32 * Nt, tk_b, 32, Nt, 256, 0, 0);
    mgemm<false, 1, false, true, 2, 1><<<dim3(Nt / 64, 4, B), blk, 0, stream>>>(
        tv_w, 256, 1, 0, xtT, 256, sXt, v_t, Nt, sXt, tv_b, 256, Nt, 256, 0, 0);
    mgemm<false, 1, false, true, 2, 1><<<dim3(Ns / 64, 1, B), blk, 0, stream>>>(
        sq_w, 256, 1, 0, xsT, 256, sXs, q_s, Ns, (long)32 * Ns, sq_b, 32, Ns, 256, 0, 0);
    mgemm<false, 1, false, true, 2, 1><<<dim3(Ns / 64, 1, B), blk, 0, stream>>>(
        sk_w, 256, 1, 0, xsT, 256, sXs, k_s, Ns, (long)32 * Ns, sk_b, 32, Ns, 256, 0, 0);
    mgemm<false, 1, false, true, 2, 1><<<dim3(Ns / 64, 4, B), blk, 0, stream>>>(
        sv_w, 256, 1, 0, xsT, 256, sXs, v_s, Ns, sXs, sv_b, 256, Ns, 256, 0, 0);

    // ---- 3) gram matrices (BMODE1, K-split 4) ----
    mgemm<false, 1, false, false, 1, 4><<<dim3(4, 16, B), blk, 0, stream>>>(
        xt32, Nt, 1, sXt, xt32, Nt, sXt, gram_t, 256, (long)C * C, nullptr, 256, 256, Nt, 0, 0);
    mgemm<false, 1, false, false, 1, 4><<<dim3(4, 16, B), blk, 0, stream>>>(
        xs32, Ns, 1, sXs, xs32, Ns, sXs, gram_s, 256, (long)C * C, nullptr, 256, 256, Ns, 0, 0);

    // ---- 4) M ----
    gram_sm_k<<<dim3(B, 4), dim3(64), 0, stream>>>(gram_t, gram_s, Mc);

    // ---- 5) channel attention (B = x^T, BMODE1) ----
    mgemm<false, 1, true, false, 2, 2><<<dim3(Nt / 64, 8, B), blk, 0, stream>>>(
        Mc, 256, 1, (long)C * C, xtT, 256, sXt, at, Nt, sXt, nullptr, 256, Nt, 256, 0, 0);
    mgemm<false, 1, true, false, 2, 1><<<dim3(Ns / 64, 4, B), blk, 0, stream>>>(
        Mc, 256, 1, (long)C * C, xsT, 256, sXs, asr, Ns, sXs, nullptr, 256, Ns, 256, 0, 0);

    // ---- 6) template spatial attention (transposed logits) ----
    mgemm<true, 0, false, false, 2, 1><<<dim3(4, 4, B), blk, 0, stream>>>(
        k_t, Nt, 1, (long)32 * Nt, q_t, Nt, (long)32 * Nt, att_t, Nt, (long)Nt * Nt,
        nullptr, Nt, Nt, 32, 0, 0);
    softmax_b_k<<<dim3((Nt * Nt) / 256), blk, 0, stream>>>(att_t, (long)Nt * Nt);
    mgemm<false, 1, true, false, 2, 2><<<dim3(Nt / 64, 8, B), blk, 0, stream>>>(
        v_t, Nt, 1, sXt, att_t, Nt, (long)Nt * Nt, at, Nt, sXt, nullptr, 256, Nt, Nt, 0, 0);

    // ---- 7) search spatial attention, 4 m-slabs (transposed logits) ----
    for (int m0s = 0; m0s < Ns; m0s += 256) {
        mgemm<true, 0, false, false, 2, 1><<<dim3(Ns / 64, 4, B), blk, 0, stream>>>(
            k_s + m0s, Ns, 1, (long)32 * Ns, q_s, Ns, (long)32 * Ns,
            att_slab, Ns, (long)256 * Ns, nullptr, 256, Ns, 32, 0, 0);
        softmax_b_k<<<dim3((256 * Ns) / 256), blk, 0, stream>>>(att_slab, (long)256 * Ns);
        mgemm<false, 1, true, false, 2, 4><<<dim3(4, 16, B), blk, 0, stream>>>(
            v_s, Ns, 1, sXs, att_slab, Ns, (long)256 * Ns,
            asr + m0s, Ns, sXs, nullptr, 256, 256, Ns, 0, 0);
    }

    // ---- 8) offset convs (im2col, K-split 4, bias prefilled) ----
    mgemm<false, 3, false, false, 2, 4><<<dim3(Nt / 64, 4, B), blk, 0, stream>>>(
        t_off_w, 2304, 1, 0, at, Nt, sXt, oo_t, Nt, (long)27 * Nt,
        nullptr, 27, Nt, 2304, 16, 4);
    mgemm<false, 3, false, false, 2, 4><<<dim3(Ns / 64, 4, B), blk, 0, stream>>>(
        s_off_w, 2304, 1, 0, asr, Ns, sXs, oo_s, Ns, (long)27 * Ns,
        nullptr, 27, Ns, 2304, 32, 5);

    // ---- 9) DCN prep (v_s region now dead) ----
    wre2_k<<<dim3((2304 * 256) / 256), blk, 0, stream>>>(t_dcn_w, Wh_t, Wl_t);
    wre2_k<<<dim3((2304 * 256) / 256), blk, 0, stream>>>(s_dcn_w, Wh_s, Wl_s);
    dcnw_k<<<dim3((B * 9 * Nt) / 256), blk, 0, stream>>>(oo_t, Tw_t, Ta_t, Nt, 16, 16);
    dcnw_k<<<dim3((B * 9 * Ns) / 256), blk, 0, stream>>>(oo_s, Tw_s, Ta_s, Ns, 32, 32);

    // ---- 10) fused deformable convs (v3: K-split for 3 blocks/CU) ----
    fill_k<<<dim3((B * C * Nt + 255) / 256), blk, 0, stream>>>(
        out_t_f32, t_dcn_b, (long)C * Nt, Nt, (long)B * C * Nt);
    fill_k<<<dim3((B * C * Ns + 255) / 256), blk, 0, stream>>>(
        out_s_f32, s_dcn_b, (long)C * Ns, Ns, (long)B * C * Ns);
    dcn2_k<12, 1><<<dim3(768), blk, 0, stream>>>(
        Wh_t, Wl_t, Tw_t, Ta_t, at, out_t_f32, Nt);
    dcn2_k<3, 4><<<dim3(768), blk, 0, stream>>>(
        Wh_s, Wl_s, Tw_s, Ta_s, asr, out_s_f32, Ns);

    // ---- 11) emit output ----
    long nt = (long)B * C * Nt;
    long ntot = nt + (long)B * C * Ns;
    cast_out_k<<<dim3((unsigned)((ntot + 255) / 256)), blk, 0, stream>>>(
        out_t_f32, out_s_f32, d_out, nt, ntot, flag);
}